// Round 1
// baseline (86.190 us; speedup 1.0000x reference)
//
#include <hip/hip_runtime.h>
#include <math.h>

#define N_   256
#define B_   256
#define DM   1024
#define KH   1280   // n*5
#define PI24 0.13089969389957473f

// ws layout (in floats)
#define WS_H      0                     // 256*1024 = 262144 floats (GEMM1 output, zeroed)
#define WS_CONST  (B_*DM)               // 256*8 per-batch constants
#define WS_WT     (WS_CONST + B_*8)     // 65536 float2 : (w0, relu(S)) transposed [j][i]

// ---------------------------------------------------------------------------
// K1: fp32 GEMM  h = history @ W1   (M=256, K=1280, N=1024), K-split=8
// ---------------------------------------------------------------------------
__global__ __launch_bounds__(256) void k_gemm1(const float* __restrict__ A,
                                               const float* __restrict__ Bw,
                                               float* __restrict__ H) {
    const int BM = 64, BN = 64, BK = 32;
    __shared__ float As[BK][68];   // A stored transposed: As[k][m], stride 68 (16B-aligned, bank-spread)
    __shared__ float Bs[BK][68];   // Bs[k][n]

    int bid = blockIdx.x;
    int mt = bid & 3;            // 4 m-tiles
    int nt = (bid >> 2) & 15;    // 16 n-tiles
    int ks = bid >> 6;           // 8 k-splits
    int m0 = mt * BM, n0 = nt * BN, k0 = ks * 160;

    int tid = threadIdx.x;
    int ty = tid >> 4, tx = tid & 15;
    int aRow = tid >> 3;          // 0..31
    int aCol = (tid & 7) * 4;     // 0..28
    int bRow = tid >> 4;          // 0..15
    int bCol = (tid & 15) * 4;    // 0..60

    float4 aV[2], bV[2];
    const int NT = 5;            // 160 / 32
    {
        int k = k0;
        aV[0] = *(const float4*)&A[(m0 + aRow) * KH + k + aCol];
        aV[1] = *(const float4*)&A[(m0 + aRow + 32) * KH + k + aCol];
        bV[0] = *(const float4*)&Bw[(k + bRow) * DM + n0 + bCol];
        bV[1] = *(const float4*)&Bw[(k + bRow + 16) * DM + n0 + bCol];
    }
    float acc[4][4];
#pragma unroll
    for (int r = 0; r < 4; r++)
#pragma unroll
        for (int c = 0; c < 4; c++) acc[r][c] = 0.f;

    for (int t = 0; t < NT; ++t) {
        __syncthreads();
        {
            const float* av0 = (const float*)&aV[0];
            const float* av1 = (const float*)&aV[1];
#pragma unroll
            for (int c = 0; c < 4; c++) As[aCol + c][aRow] = av0[c];
#pragma unroll
            for (int c = 0; c < 4; c++) As[aCol + c][aRow + 32] = av1[c];
            *(float4*)&Bs[bRow][bCol] = bV[0];
            *(float4*)&Bs[bRow + 16][bCol] = bV[1];
        }
        __syncthreads();
        if (t + 1 < NT) {
            int k = k0 + (t + 1) * BK;
            aV[0] = *(const float4*)&A[(m0 + aRow) * KH + k + aCol];
            aV[1] = *(const float4*)&A[(m0 + aRow + 32) * KH + k + aCol];
            bV[0] = *(const float4*)&Bw[(k + bRow) * DM + n0 + bCol];
            bV[1] = *(const float4*)&Bw[(k + bRow + 16) * DM + n0 + bCol];
        }
#pragma unroll
        for (int kk = 0; kk < BK; ++kk) {
            float4 a = *(const float4*)&As[kk][ty * 4];
            float4 b = *(const float4*)&Bs[kk][tx * 4];
            float av[4] = {a.x, a.y, a.z, a.w};
            float bv[4] = {b.x, b.y, b.z, b.w};
#pragma unroll
            for (int r = 0; r < 4; r++)
#pragma unroll
                for (int c = 0; c < 4; c++)
                    acc[r][c] = fmaf(av[r], bv[c], acc[r][c]);
        }
    }
#pragma unroll
    for (int r = 0; r < 4; r++)
#pragma unroll
        for (int c = 0; c < 4; c++)
            atomicAdd(&H[(m0 + ty * 4 + r) * DM + n0 + tx * 4 + c], acc[r][c]);
}

// ---------------------------------------------------------------------------
// K2: per-batch head: +b1, LayerNorm, ReLU, @W2(1024x4)+b2, tanh/sigmoid
// ---------------------------------------------------------------------------
__global__ __launch_bounds__(256) void k_head(const float* __restrict__ H,
                                              const float* __restrict__ b1,
                                              const float* __restrict__ lg,
                                              const float* __restrict__ lb,
                                              const float* __restrict__ W2,
                                              const float* __restrict__ b2,
                                              const float* __restrict__ phi_prev,
                                              float* __restrict__ out,
                                              float* __restrict__ consts) {
    int b = blockIdx.x, tid = threadIdx.x;
    __shared__ float red[256];
    __shared__ float red2[256];
    __shared__ float4 redp[256];

    float4 h4  = *(const float4*)&H[b * DM + tid * 4];
    float4 b14 = *(const float4*)&b1[tid * 4];
    float hv[4] = {h4.x + b14.x, h4.y + b14.y, h4.z + b14.z, h4.w + b14.w};
    float s = 0.f, s2 = 0.f;
#pragma unroll
    for (int e = 0; e < 4; e++) { s += hv[e]; s2 += hv[e] * hv[e]; }
    red[tid] = s; red2[tid] = s2;
    __syncthreads();
    for (int off = 128; off > 0; off >>= 1) {
        if (tid < off) { red[tid] += red[tid + off]; red2[tid] += red2[tid + off]; }
        __syncthreads();
    }
    float mean = red[0] * (1.f / DM);
    float var  = red2[0] * (1.f / DM) - mean * mean;
    float rstd = rsqrtf(var + 1e-5f);

    float4 g4  = *(const float4*)&lg[tid * 4];
    float4 be4 = *(const float4*)&lb[tid * 4];
    float gv[4]  = {g4.x, g4.y, g4.z, g4.w};
    float bev[4] = {be4.x, be4.y, be4.z, be4.w};
    float p0 = 0.f, p1 = 0.f, p2 = 0.f, p3 = 0.f;
#pragma unroll
    for (int e = 0; e < 4; e++) {
        float y = (hv[e] - mean) * rstd * gv[e] + bev[e];
        y = fmaxf(y, 0.f);
        float4 w = *(const float4*)&W2[(tid * 4 + e) * 4];
        p0 = fmaf(y, w.x, p0); p1 = fmaf(y, w.y, p1);
        p2 = fmaf(y, w.z, p2); p3 = fmaf(y, w.w, p3);
    }
    redp[tid] = make_float4(p0, p1, p2, p3);
    __syncthreads();
    for (int off = 128; off > 0; off >>= 1) {
        if (tid < off) {
            float4 o = redp[tid + off];
            redp[tid].x += o.x; redp[tid].y += o.y;
            redp[tid].z += o.z; redp[tid].w += o.w;
        }
        __syncthreads();
    }
    if (tid == 0) {
        float P0 = redp[0].x + b2[0];
        float P1 = redp[0].y + b2[1];
        float P2 = redp[0].z + b2[2];
        float P3 = redp[0].w + b2[3];
        float dphi0 = tanhf(P0) * PI24;
        float dphi1 = tanhf(P2) * PI24;
        float phi0 = phi_prev[b * 2 + 0] + dphi0;
        float phi1 = phi_prev[b * 2 + 1] + dphi1;
        float r0 = 1.f / (1.f + expf(-P1));
        float r1 = 1.f / (1.f + expf(-P3));
        out[B_ * N_ * 2 + b * 2 + 0] = phi0;
        out[B_ * N_ * 2 + b * 2 + 1] = phi1;
        out[B_ * N_ * 2 + B_ * 2 + b * 2 + 0] = dphi0;
        out[B_ * N_ * 2 + B_ * 2 + b * 2 + 1] = dphi1;
        float* cb = &consts[b * 8];
        cb[0] = phi0 - phi1;   // delta
        cb[1] = r1;
        cb[2] = r0 - r1;       // dr
        cb[3] = cosf(phi1);
        cb[4] = sinf(phi1);
    }
}

// ---------------------------------------------------------------------------
// K3: per (i,j): w0 = softmax0 = sigmoid(p0-p1), s = relu(S); store (w0,s)
// transposed [j][i] as float2 for coalesced reads in the main loop.
// ---------------------------------------------------------------------------
__global__ __launch_bounds__(256) void k_prep(const float* __restrict__ pw,
                                              const float* __restrict__ S,
                                              float2* __restrict__ wT) {
    __shared__ float2 tile[64][65];
    int bi = blockIdx.x >> 2, bj = blockIdx.x & 3;
    int i0 = bi * 64, j0 = bj * 64;
    int tid = threadIdx.x;
#pragma unroll
    for (int rep = 0; rep < 16; ++rep) {
        int idx = rep * 256 + tid;
        int r = idx >> 6, c = idx & 63;       // r: local i, c: local j
        float2 p = *(const float2*)&pw[((i0 + r) * N_ + j0 + c) * 2];
        float sv = S[(i0 + r) * N_ + j0 + c];
        float w0 = 1.f / (1.f + expf(p.y - p.x));
        tile[r][c] = make_float2(w0, fmaxf(sv, 0.f));
    }
    __syncthreads();
#pragma unroll
    for (int rep = 0; rep < 16; ++rep) {
        int idx = rep * 256 + tid;
        int r = idx >> 6, c = idx & 63;       // r: local j, c: local i
        wT[(j0 + r) * N_ + i0 + c] = tile[c][r];
    }
}

// ---------------------------------------------------------------------------
// K4: main loop. Block = (group of 4 batches) x (j-chunk of 32); thread = i.
// acc = sum_j A * e^{i w0*delta} * x ; rotate by e^{i phi1}; atomicAdd out.
// ---------------------------------------------------------------------------
__global__ __launch_bounds__(256) void k_main(const float2* __restrict__ wT,
                                              const float* __restrict__ consts,
                                              const float* __restrict__ x2,
                                              float* __restrict__ out) {
    int bid = blockIdx.x;
    int grp = bid >> 3, jc = bid & 7;
    int b0 = grp * 4, j0 = jc * 32;
    int i = threadIdx.x;

    __shared__ float xs[4][64];
    {
        int t = threadIdx.x;
        int nb = t >> 6, rem = t & 63;
        xs[nb][rem] = x2[(b0 + nb) * (N_ * 2) + j0 * 2 + rem];
    }
    float delta[4], r1[4], dr[4];
#pragma unroll
    for (int nb = 0; nb < 4; nb++) {
        const float* cb = &consts[(b0 + nb) * 8];
        delta[nb] = cb[0]; r1[nb] = cb[1]; dr[nb] = cb[2];
    }
    __syncthreads();

    float accr[4] = {0.f, 0.f, 0.f, 0.f};
    float acci[4] = {0.f, 0.f, 0.f, 0.f};
#pragma unroll 4
    for (int jj = 0; jj < 32; ++jj) {
        int j = j0 + jj;
        float2 ws = wT[j * N_ + i];
        float w0 = ws.x, sv = ws.y;
        float xr0 = xs[0][jj * 2], xi0 = xs[0][jj * 2 + 1];
        float xr1 = xs[1][jj * 2], xi1 = xs[1][jj * 2 + 1];
        float xr2 = xs[2][jj * 2], xi2 = xs[2][jj * 2 + 1];
        float xr3 = xs[3][jj * 2], xi3 = xs[3][jj * 2 + 1];
        float xr[4] = {xr0, xr1, xr2, xr3};
        float xi[4] = {xi0, xi1, xi2, xi3};
#pragma unroll
        for (int nb = 0; nb < 4; nb++) {
            float r = fmaf(w0, dr[nb], r1[nb]);
            float g = r * sv;                          // in (0, 0.4)
            float u = g * g;
            // tanh(g) ~= g*(1 + u*(-1/3 + u*(2/15 - u*17/315))), |err|<6e-6 on [0,0.45]
            float tp = fmaf(u, fmaf(u, fmaf(u, -0.05396825396825397f,
                                            0.13333333333333333f),
                                    -0.3333333333333333f), 1.0f);
            float A = 1.1f * g * tp;
            float ang = w0 * delta[nb];
            float sn = __sinf(ang);
            float cs = __cosf(ang);
            float ar = A * cs, as = A * sn;
            accr[nb] = fmaf(ar, xr[nb], accr[nb]);
            accr[nb] = fmaf(-as, xi[nb], accr[nb]);
            acci[nb] = fmaf(as, xr[nb], acci[nb]);
            acci[nb] = fmaf(ar, xi[nb], acci[nb]);
        }
    }
#pragma unroll
    for (int nb = 0; nb < 4; nb++) {
        const float* cb = &consts[(b0 + nb) * 8];
        float c1 = cb[3], s1 = cb[4];
        float outr = c1 * accr[nb] - s1 * acci[nb];
        float outi = s1 * accr[nb] + c1 * acci[nb];
        int o = ((b0 + nb) * N_ + i) * 2;
        atomicAdd(&out[o], outr);
        atomicAdd(&out[o + 1], outi);
    }
}

// ---------------------------------------------------------------------------
extern "C" void kernel_launch(void* const* d_in, const int* in_sizes, int n_in,
                              void* d_out, int out_size, void* d_ws, size_t ws_size,
                              hipStream_t stream) {
    const float* x_2ch    = (const float*)d_in[0];
    const float* history  = (const float*)d_in[1];
    const float* phi_prev = (const float*)d_in[2];
    const float* S        = (const float*)d_in[3];
    const float* W1       = (const float*)d_in[4];
    const float* b1       = (const float*)d_in[5];
    const float* ln_g     = (const float*)d_in[6];
    const float* ln_b     = (const float*)d_in[7];
    const float* W2       = (const float*)d_in[8];
    const float* b2       = (const float*)d_in[9];
    const float* path_w   = (const float*)d_in[10];

    float* out = (float*)d_out;
    float* ws  = (float*)d_ws;
    float*  ws_h   = ws + WS_H;
    float*  consts = ws + WS_CONST;
    float2* wT     = (float2*)(ws + WS_WT);

    // zero the atomic accumulation targets (out poisoned before timing; ws too)
    hipMemsetAsync(d_out, 0, (size_t)out_size * sizeof(float), stream);
    hipMemsetAsync(ws_h, 0, (size_t)B_ * DM * sizeof(float), stream);

    k_gemm1<<<512, 256, 0, stream>>>(history, W1, ws_h);
    k_prep <<<16,  256, 0, stream>>>(path_w, S, wT);
    k_head <<<256, 256, 0, stream>>>(ws_h, b1, ln_g, ln_b, W2, b2, phi_prev, out, consts);
    k_main <<<512, 256, 0, stream>>>(wT, consts, x_2ch, out);
}

// Round 2
// 42.982 us; speedup vs baseline: 2.0052x; 2.0052x over previous
//
#include <hip/hip_runtime.h>
#include <math.h>

#define N_   256
#define B_   256
#define DM   1024
#define KH   1280   // n*5
#define PI24 0.13089969389957473f

// ws layout (floats):
//   consts : [0, 2048)            8 per batch
//   wT     : [2048, 2048+131072)  65536 float2 (w0, relu(S)) transposed [j][i]
//   Hp     : partials, splits * B_*DM floats
#define WS_CONST 0
#define WS_WT    2048
#define WS_PART  (2048 + 131072)

// ---------------------------------------------------------------------------
// K1: fp32 GEMM  h = history @ W1  (M=256,K=1280,N=1024), split-K -> partials
// ---------------------------------------------------------------------------
__global__ __launch_bounds__(256) void k_gemm1(const float* __restrict__ A,
                                               const float* __restrict__ Bw,
                                               float* __restrict__ Hp,
                                               int kchunk) {
    const int BK = 32;
    __shared__ float As[BK][68];   // As[k][m]
    __shared__ float Bs[BK][68];   // Bs[k][n]

    int bid = blockIdx.x;
    int mt = bid & 3;            // 4 m-tiles (64)
    int nt = (bid >> 2) & 15;    // 16 n-tiles (64)
    int ks = bid >> 6;           // split index
    int m0 = mt * 64, n0 = nt * 64, k0 = ks * kchunk;
    int NT = kchunk >> 5;        // kchunk / 32

    int tid = threadIdx.x;
    int ty = tid >> 4, tx = tid & 15;
    int aRow = tid >> 3;          // 0..31
    int aCol = (tid & 7) * 4;     // 0..28
    int bRow = tid >> 4;          // 0..15
    int bCol = (tid & 15) * 4;    // 0..60

    float4 aV[2], bV[2];
    {
        int k = k0;
        aV[0] = *(const float4*)&A[(m0 + aRow) * KH + k + aCol];
        aV[1] = *(const float4*)&A[(m0 + aRow + 32) * KH + k + aCol];
        bV[0] = *(const float4*)&Bw[(k + bRow) * DM + n0 + bCol];
        bV[1] = *(const float4*)&Bw[(k + bRow + 16) * DM + n0 + bCol];
    }
    float acc[4][4];
#pragma unroll
    for (int r = 0; r < 4; r++)
#pragma unroll
        for (int c = 0; c < 4; c++) acc[r][c] = 0.f;

    for (int t = 0; t < NT; ++t) {
        __syncthreads();
        {
            const float* av0 = (const float*)&aV[0];
            const float* av1 = (const float*)&aV[1];
#pragma unroll
            for (int c = 0; c < 4; c++) As[aCol + c][aRow] = av0[c];
#pragma unroll
            for (int c = 0; c < 4; c++) As[aCol + c][aRow + 32] = av1[c];
            *(float4*)&Bs[bRow][bCol] = bV[0];
            *(float4*)&Bs[bRow + 16][bCol] = bV[1];
        }
        __syncthreads();
        if (t + 1 < NT) {
            int k = k0 + (t + 1) * BK;
            aV[0] = *(const float4*)&A[(m0 + aRow) * KH + k + aCol];
            aV[1] = *(const float4*)&A[(m0 + aRow + 32) * KH + k + aCol];
            bV[0] = *(const float4*)&Bw[(k + bRow) * DM + n0 + bCol];
            bV[1] = *(const float4*)&Bw[(k + bRow + 16) * DM + n0 + bCol];
        }
#pragma unroll
        for (int kk = 0; kk < BK; ++kk) {
            float4 a = *(const float4*)&As[kk][ty * 4];
            float4 b = *(const float4*)&Bs[kk][tx * 4];
            float av[4] = {a.x, a.y, a.z, a.w};
            float bv[4] = {b.x, b.y, b.z, b.w};
#pragma unroll
            for (int r = 0; r < 4; r++)
#pragma unroll
                for (int c = 0; c < 4; c++)
                    acc[r][c] = fmaf(av[r], bv[c], acc[r][c]);
        }
    }
    float* P = Hp + (size_t)ks * (B_ * DM);
#pragma unroll
    for (int r = 0; r < 4; r++) {
        float4 v = make_float4(acc[r][0], acc[r][1], acc[r][2], acc[r][3]);
        *(float4*)&P[(m0 + ty * 4 + r) * DM + n0 + tx * 4] = v;
    }
}

// ---------------------------------------------------------------------------
// K2: per-batch head: sum split-K partials, +b1, LayerNorm, ReLU, @W2+b2,
// tanh/sigmoid -> phi/dphi outputs + per-batch consts
// ---------------------------------------------------------------------------
__global__ __launch_bounds__(256) void k_head(const float* __restrict__ Hp,
                                              int splits,
                                              const float* __restrict__ b1,
                                              const float* __restrict__ lg,
                                              const float* __restrict__ lb,
                                              const float* __restrict__ W2,
                                              const float* __restrict__ b2,
                                              const float* __restrict__ phi_prev,
                                              float* __restrict__ out,
                                              float* __restrict__ consts) {
    int b = blockIdx.x, tid = threadIdx.x;
    __shared__ float red[256];
    __shared__ float red2[256];
    __shared__ float4 redp[256];

    float4 b14 = *(const float4*)&b1[tid * 4];
    float hv[4] = {b14.x, b14.y, b14.z, b14.w};
    for (int s = 0; s < splits; ++s) {
        float4 p = *(const float4*)&Hp[(size_t)s * (B_ * DM) + b * DM + tid * 4];
        hv[0] += p.x; hv[1] += p.y; hv[2] += p.z; hv[3] += p.w;
    }
    float s = 0.f, s2 = 0.f;
#pragma unroll
    for (int e = 0; e < 4; e++) { s += hv[e]; s2 += hv[e] * hv[e]; }
    red[tid] = s; red2[tid] = s2;
    __syncthreads();
    for (int off = 128; off > 0; off >>= 1) {
        if (tid < off) { red[tid] += red[tid + off]; red2[tid] += red2[tid + off]; }
        __syncthreads();
    }
    float mean = red[0] * (1.f / DM);
    float var  = red2[0] * (1.f / DM) - mean * mean;
    float rstd = rsqrtf(var + 1e-5f);

    float4 g4  = *(const float4*)&lg[tid * 4];
    float4 be4 = *(const float4*)&lb[tid * 4];
    float gv[4]  = {g4.x, g4.y, g4.z, g4.w};
    float bev[4] = {be4.x, be4.y, be4.z, be4.w};
    float p0 = 0.f, p1 = 0.f, p2 = 0.f, p3 = 0.f;
#pragma unroll
    for (int e = 0; e < 4; e++) {
        float y = (hv[e] - mean) * rstd * gv[e] + bev[e];
        y = fmaxf(y, 0.f);
        float4 w = *(const float4*)&W2[(tid * 4 + e) * 4];
        p0 = fmaf(y, w.x, p0); p1 = fmaf(y, w.y, p1);
        p2 = fmaf(y, w.z, p2); p3 = fmaf(y, w.w, p3);
    }
    redp[tid] = make_float4(p0, p1, p2, p3);
    __syncthreads();
    for (int off = 128; off > 0; off >>= 1) {
        if (tid < off) {
            float4 o = redp[tid + off];
            redp[tid].x += o.x; redp[tid].y += o.y;
            redp[tid].z += o.z; redp[tid].w += o.w;
        }
        __syncthreads();
    }
    if (tid == 0) {
        float P0 = redp[0].x + b2[0];
        float P1 = redp[0].y + b2[1];
        float P2 = redp[0].z + b2[2];
        float P3 = redp[0].w + b2[3];
        float dphi0 = tanhf(P0) * PI24;
        float dphi1 = tanhf(P2) * PI24;
        float phi0 = phi_prev[b * 2 + 0] + dphi0;
        float phi1 = phi_prev[b * 2 + 1] + dphi1;
        float r0 = 1.f / (1.f + expf(-P1));
        float r1 = 1.f / (1.f + expf(-P3));
        out[B_ * N_ * 2 + b * 2 + 0] = phi0;
        out[B_ * N_ * 2 + b * 2 + 1] = phi1;
        out[B_ * N_ * 2 + B_ * 2 + b * 2 + 0] = dphi0;
        out[B_ * N_ * 2 + B_ * 2 + b * 2 + 1] = dphi1;
        float* cb = &consts[b * 8];
        cb[0] = phi0 - phi1;   // delta (radians)
        cb[1] = r1;
        cb[2] = r0 - r1;       // dr
        cb[3] = cosf(phi1);
        cb[4] = sinf(phi1);
    }
}

// ---------------------------------------------------------------------------
// K3: per (i,j): w0 = sigmoid(p0-p1), s = relu(S); store transposed [j][i]
// ---------------------------------------------------------------------------
__global__ __launch_bounds__(256) void k_prep(const float* __restrict__ pw,
                                              const float* __restrict__ S,
                                              float2* __restrict__ wT) {
    __shared__ float2 tile[32][33];
    int bi = blockIdx.x >> 3, bj = blockIdx.x & 7;
    int i0 = bi * 32, j0 = bj * 32;
    int tid = threadIdx.x;
#pragma unroll
    for (int rep = 0; rep < 4; ++rep) {
        int idx = rep * 256 + tid;
        int r = idx >> 5, c = idx & 31;       // r: local i, c: local j
        float2 p = *(const float2*)&pw[((i0 + r) * N_ + j0 + c) * 2];
        float sv = S[(i0 + r) * N_ + j0 + c];
        float w0 = 1.f / (1.f + __expf(p.y - p.x));
        tile[r][c] = make_float2(w0, fmaxf(sv, 0.f));
    }
    __syncthreads();
#pragma unroll
    for (int rep = 0; rep < 4; ++rep) {
        int idx = rep * 256 + tid;
        int r = idx >> 5, c = idx & 31;       // r: local j, c: local i
        wT[(j0 + r) * N_ + i0 + c] = tile[c][r];
    }
}

// ---------------------------------------------------------------------------
// K4: main loop. One block per batch; 512 threads = (jhalf 0/1) x (i 0..255).
// Each thread sums its 128 j's; halves combined via LDS; no atomics.
// ---------------------------------------------------------------------------
__global__ __launch_bounds__(512) void k_main(const float2* __restrict__ wT,
                                              const float* __restrict__ consts,
                                              const float* __restrict__ x2,
                                              float* __restrict__ out) {
    int b = blockIdx.x;
    int tid = threadIdx.x;
    int i = tid & 255, jh = tid >> 8;

    __shared__ float2 xs[256];     // x2[b] as (re,im) pairs
    __shared__ float2 sred[256];
    ((float*)xs)[tid] = x2[b * (N_ * 2) + tid];

    const float* cb = &consts[b * 8];
    float delta = cb[0], r1 = cb[1], dr = cb[2], c1 = cb[3], s1 = cb[4];
    __syncthreads();

    int jbase = jh * 128;
    const float2* wp = &wT[jbase * N_ + i];

    float ar0 = 0.f, ai0 = 0.f, ar1 = 0.f, ai1 = 0.f;
#pragma unroll 4
    for (int jj = 0; jj < 128; jj += 2) {
        // --- even j ---
        {
            float2 w = wp[(size_t)jj * N_];
            float r = fmaf(w.x, dr, r1);
            float g = r * w.y;                       // in (0, 0.4)
            float u = g * g;
            // 1.1*tanh(g) = g*(1.1 + u*(-1.1/3 + u*(2.2/15 - u*1.1*17/315)))
            float tp = fmaf(u, fmaf(u, fmaf(u, -0.059365079f, 0.14666667f),
                                    -0.36666667f), 1.1f);
            float A = g * tp;
            float ang = w.x * delta;
            float sn = __sinf(ang);
            float cs = __cosf(ang);
            float2 xv = xs[jbase + jj];
            float ar = A * cs, as_ = A * sn;
            ar0 = fmaf(ar, xv.x, ar0); ar0 = fmaf(-as_, xv.y, ar0);
            ai0 = fmaf(as_, xv.x, ai0); ai0 = fmaf(ar, xv.y, ai0);
        }
        // --- odd j ---
        {
            float2 w = wp[(size_t)(jj + 1) * N_];
            float r = fmaf(w.x, dr, r1);
            float g = r * w.y;
            float u = g * g;
            float tp = fmaf(u, fmaf(u, fmaf(u, -0.059365079f, 0.14666667f),
                                    -0.36666667f), 1.1f);
            float A = g * tp;
            float ang = w.x * delta;
            float sn = __sinf(ang);
            float cs = __cosf(ang);
            float2 xv = xs[jbase + jj + 1];
            float ar = A * cs, as_ = A * sn;
            ar1 = fmaf(ar, xv.x, ar1); ar1 = fmaf(-as_, xv.y, ar1);
            ai1 = fmaf(as_, xv.x, ai1); ai1 = fmaf(ar, xv.y, ai1);
        }
    }
    float accr = ar0 + ar1, acci = ai0 + ai1;
    if (jh == 1) sred[i] = make_float2(accr, acci);
    __syncthreads();
    if (jh == 0) {
        float2 o = sred[i];
        accr += o.x; acci += o.y;
        float outr = c1 * accr - s1 * acci;
        float outi = s1 * accr + c1 * acci;
        ((float2*)out)[b * N_ + i] = make_float2(outr, outi);
    }
}

// ---------------------------------------------------------------------------
extern "C" void kernel_launch(void* const* d_in, const int* in_sizes, int n_in,
                              void* d_out, int out_size, void* d_ws, size_t ws_size,
                              hipStream_t stream) {
    const float* x_2ch    = (const float*)d_in[0];
    const float* history  = (const float*)d_in[1];
    const float* phi_prev = (const float*)d_in[2];
    const float* S        = (const float*)d_in[3];
    const float* W1       = (const float*)d_in[4];
    const float* b1       = (const float*)d_in[5];
    const float* ln_g     = (const float*)d_in[6];
    const float* ln_b     = (const float*)d_in[7];
    const float* W2       = (const float*)d_in[8];
    const float* b2       = (const float*)d_in[9];
    const float* path_w   = (const float*)d_in[10];

    float* out = (float*)d_out;
    float* ws  = (float*)d_ws;
    float*  consts = ws + WS_CONST;
    float2* wT     = (float2*)(ws + WS_WT);
    float*  Hp     = ws + WS_PART;

    // pick split-K count that fits in ws
    size_t avail_f = ws_size / 4 - WS_PART;
    int splits = 8;
    while (splits > 1 && (size_t)splits * (B_ * DM) > avail_f) splits >>= 1;
    int kchunk = KH / splits;

    k_gemm1<<<64 * splits, 256, 0, stream>>>(history, W1, Hp, kchunk);
    k_prep <<<64,  256, 0, stream>>>(path_w, S, wT);
    k_head <<<256, 256, 0, stream>>>(Hp, splits, b1, ln_g, ln_b, W2, b2, phi_prev, out, consts);
    k_main <<<256, 512, 0, stream>>>(wT, consts, x_2ch, out);
}